// Round 3
// baseline (420.737 us; speedup 1.0000x reference)
//
#include <hip/hip_runtime.h>
#include <stdint.h>

typedef unsigned short u16;
typedef __bf16 bf16x8 __attribute__((ext_vector_type(8)));
typedef float f32x4 __attribute__((ext_vector_type(4)));
typedef unsigned short u16x8 __attribute__((ext_vector_type(8)));

// ---------- helpers ----------
__device__ __forceinline__ u16 f2b(float f) {
  union { float f; uint32_t u; } v; v.f = f;
  uint32_t r = v.u + 0x7fffu + ((v.u >> 16) & 1u);
  return (u16)(r >> 16);
}
__device__ __forceinline__ float b2f(u16 b) {
  union { float f; uint32_t u; } v; v.u = ((uint32_t)b) << 16;
  return v.f;
}
// async 16B/lane global->LDS (dest = uniform base + lane*16)
__device__ __forceinline__ void g2l16(const void* g, void* l) {
  __builtin_amdgcn_global_load_lds(
      (const __attribute__((address_space(1))) void*)g,
      (__attribute__((address_space(3))) void*)l, 16, 0, 0);
}

#define N_SAMP 128
#define OPAD   224
#define ROWS   (N_SAMP * OPAD)   // 28672

// ---------- K0: fused prep: zero convAcc/relations, repack weights, fill qe ----------
// block ranges: [0,3584) zero convAcc | [3584,3616) zero relations |
// [3616,4128) W2 repack | [4128,4416) hp_w0t | [4416,4704) gt_w0t |
// [4704,4960) gt_w1t | [4960,5088) qe-fill (one block per n)
__global__ __launch_bounds__(256) void prep_misc(
    const float* __restrict__ conv_w, const float* __restrict__ hp_w0,
    const float* __restrict__ gt_w0, const float* __restrict__ gt_w1,
    const float* __restrict__ code,
    u16* __restrict__ W2, u16* __restrict__ hp_w0t,
    u16* __restrict__ gt_w0t, u16* __restrict__ gt_w1t,
    u16* __restrict__ qeb, float* __restrict__ convAcc,
    float* __restrict__ relations) {
  __shared__ float sw[2304];
  __shared__ u16 tmpl[176];
  int b = blockIdx.x, tid = threadIdx.x;
  if (b < 3584) {                       // zero convAcc (ROWS*128 floats)
    f32x4 z = {0.f, 0.f, 0.f, 0.f};
    *(f32x4*)(convAcc + ((size_t)(b * 256 + tid) << 2)) = z;
    return;
  }
  b -= 3584;
  if (b < 32) {                         // zero relations (128*256 floats)
    f32x4 z = {0.f, 0.f, 0.f, 0.f};
    *(f32x4*)(relations + ((size_t)(b * 256 + tid) << 2)) = z;
    return;
  }
  b -= 32;
  if (b < 512) {                        // W2 repack: [cf][cin][9] -> [9][cf][cin]
    size_t base = (size_t)b * 2304;
#pragma unroll
    for (int i = 0; i < 9; ++i) sw[tid + 256 * i] = conv_w[base + tid + 256 * i];
    __syncthreads();
    int f = b * 256 + tid;
    int cf = f >> 10, cin = f & 1023;
#pragma unroll
    for (int k = 0; k < 9; ++k)
      W2[(size_t)k * 131072 + cf * 1024 + cin] = f2b(sw[tid * 9 + k]);
    return;
  }
  b -= 512;
  if (b < 288) {                        // hp_w0t[256][288], K zero-padded
    int idx = b * 256 + tid;
    int nn = idx / 288, kk = idx - nn * 288;
    hp_w0t[idx] = (kk < 258) ? f2b(hp_w0[kk * 256 + nn]) : (u16)0;
    return;
  }
  b -= 288;
  if (b < 288) {                        // gt_w0t[256][288]
    int idx = b * 256 + tid;
    int nn = idx / 288, kk = idx - nn * 288;
    gt_w0t[idx] = (kk < 258) ? f2b(gt_w0[kk * 256 + nn]) : (u16)0;
    return;
  }
  b -= 288;
  if (b < 256) {                        // gt_w1t[256][256]
    int idx = b * 256 + tid;
    int nn = idx >> 8, kk = idx & 255;
    gt_w1t[idx] = f2b(gt_w1[kk * 256 + nn]);
    return;
  }
  b -= 256;
  {                                     // qe-fill for n = b : valid rows, cols 128..287
    int n = b;
    if (tid < 176) {
      int c = 128 + tid;
      u16 v = 0;
      if (c >= 130 && c < 258) v = f2b(code[n * 128 + c - 130]);
      tmpl[tid] = v;
    }
    __syncthreads();
    for (int it = 0; it < 16; ++it) {
      int ch = it * 256 + tid;
      if (ch < 3920) {                  // 196 rows x 20 chunks
        int o = ch / 20, j = ch - o * 20;
        u16x8 v = *(const u16x8*)&tmpl[j * 8];
        if (j == 0) {
          int y = o / 14, x = o - y * 14;
          v[0] = f2b(-1.f + 2.f * y / 13.f);
          v[1] = f2b(-1.f + 2.f * x / 13.f);
        }
        *(u16x8*)(qeb + (size_t)(n * 224 + o) * 288 + 128 + j * 8) = v;
      }
    }
  }
}

// ---------- K0b: image -> imgT[n][256 sp (16x16 zero-bordered)][1024 cin] bf16 ----------
__global__ __launch_bounds__(256) void prep_img(const float* __restrict__ image,
                                                u16* __restrict__ imgT) {
  __shared__ float t[64][197];
  int n = blockIdx.x >> 4;
  int cin0 = (blockIdx.x & 15) * 64;
  const float* src = image + ((size_t)n * 1024 + cin0) * 196;
  for (int e = threadIdx.x; e < 64 * 196; e += 256) {
    int c = e / 196, sp = e % 196;
    t[c][sp] = src[c * 196 + sp];
  }
  __syncthreads();
  int w = threadIdx.x >> 6, lane = threadIdx.x & 63;
  for (int i = 0; i < 64; ++i) {
    int spg = i * 4 + w;
    int gy = spg >> 4, gx = spg & 15;
    float v = 0.f;
    if (gy >= 1 && gy <= 14 && gx >= 1 && gx <= 14) v = t[lane][(gy - 1) * 14 + (gx - 1)];
    imgT[(((size_t)(n * 256 + spg)) << 10) + cin0 + lane] = f2b(v);
  }
}

// ---------- K1: conv implicit GEMM, split-K x4, B-frags direct from global ----------
// grid 1024 = 8 xcd * (16 nIdx * 2 oh * 4 ks); BK=64; LDS holds A only (14 KB).
__global__ __launch_bounds__(256, 4) void conv_gemm(
    const u16* __restrict__ imgT, const u16* __restrict__ W2,
    float* __restrict__ convAcc) {
  __shared__ __align__(16) u16 lA[112 * 64];
  int tid = threadIdx.x, lane = tid & 63, w = tid >> 6;
  int wg = blockIdx.x;
  int xcd = wg & 7, grp = wg >> 3;          // same-n blocks land on same XCD
  int nIdx = grp >> 3, r8 = grp & 7;
  int oh = r8 >> 2, ks = r8 & 3;
  int n = (nIdx << 3) | xcd;
  int oBase = oh * 112;
  size_t nBase = (size_t)n << 8;
  int rowIn = lane >> 3;
  int cA = ((lane & 7) ^ rowIn) << 3;       // XOR-swizzled chunk (elems)

  int yxA[4];
#pragma unroll
  for (int ii = 0; ii < 4; ++ii) {
    int t = w + ii * 4;
    int o = oBase + t * 8 + rowIn;
    bool valid = o < 196;
    int y = o / 14, x = o - y * 14;
    yxA[ii] = valid ? (y * 16 + x) : 0;     // invalid rows: garbage, discarded in epilogue
  }

  f32x4 acc[7][2];
#pragma unroll
  for (int mt = 0; mt < 7; ++mt)
#pragma unroll
    for (int j = 0; j < 2; ++j) acc[mt][j] = (f32x4){0.f, 0.f, 0.f, 0.f};

  int l = lane & 15, q = lane >> 4;
  const u16* Wl = W2 + ((size_t)(w * 32 + l) << 10) + q * 8;  // per-lane B row base

  for (int u = ks * 36; u < ks * 36 + 36; ++u) {
    int s = u >> 4, cb = u & 15, k0 = cb << 6;
    int s3 = s / 3;
    int off = s3 * 16 + (s - s3 * 3);       // dy*16+dx
    // B fragments: direct global->VGPR (W2 rows are K-contiguous; L2-resident)
    const u16* Wp = Wl + ((size_t)s << 17) + k0;
    bf16x8 bj0k0 = *(const bf16x8*)(Wp);
    bf16x8 bj1k0 = *(const bf16x8*)(Wp + (16 << 10));
    bf16x8 bj0k1 = *(const bf16x8*)(Wp + 32);
    bf16x8 bj1k1 = *(const bf16x8*)(Wp + (16 << 10) + 32);
    __syncthreads();
    g2l16(imgT + ((nBase + (size_t)(yxA[0] + off)) << 10) + k0 + cA, &lA[(w) * 512]);
    g2l16(imgT + ((nBase + (size_t)(yxA[1] + off)) << 10) + k0 + cA, &lA[(w + 4) * 512]);
    g2l16(imgT + ((nBase + (size_t)(yxA[2] + off)) << 10) + k0 + cA, &lA[(w + 8) * 512]);
    if (w < 2)
      g2l16(imgT + ((nBase + (size_t)(yxA[3] + off)) << 10) + k0 + cA, &lA[(w + 12) * 512]);
    __syncthreads();
#pragma unroll
    for (int kk = 0; kk < 2; ++kk) {
      int co = ((((kk << 2) | q) ^ (l & 7)) << 3);
      bf16x8 af[7];
#pragma unroll
      for (int mt = 0; mt < 7; ++mt)
        af[mt] = *(const bf16x8*)&lA[(mt * 16 + l) * 64 + co];
#pragma unroll
      for (int mt = 0; mt < 7; ++mt)
        acc[mt][0] = __builtin_amdgcn_mfma_f32_16x16x32_bf16(af[mt], kk ? bj0k1 : bj0k0,
                                                             acc[mt][0], 0, 0, 0);
#pragma unroll
      for (int mt = 0; mt < 7; ++mt)
        acc[mt][1] = __builtin_amdgcn_mfma_f32_16x16x32_bf16(af[mt], kk ? bj1k1 : bj1k0,
                                                             acc[mt][1], 0, 0, 0);
    }
  }
#pragma unroll
  for (int mt = 0; mt < 7; ++mt) {
    int o = oBase + mt * 16 + q * 4;
#pragma unroll
    for (int r4 = 0; r4 < 4; ++r4) {
      if (o + r4 < 196) {
        float* dst = convAcc + (size_t)(n * 224 + o + r4) * 128 + w * 32 + l;
        atomicAdd(dst, acc[mt][0][r4]);
        atomicAdd(dst + 16, acc[mt][1][r4]);
      }
    }
  }
}

// ---------- K1b: convAcc + bias -> qeb bf16 cols 0..127 ----------
__global__ __launch_bounds__(256) void conv_fix(
    const float* __restrict__ convAcc, const float* __restrict__ conv_b,
    u16* __restrict__ qeb) {
  int idx = blockIdx.x * 256 + threadIdx.x;   // 128*196*32
  int row196 = idx >> 5;
  int c0 = (idx & 31) << 2;
  int n = row196 / 196, o = row196 - n * 196;
  size_t row = (size_t)(n * 224 + o);
  const float4 v = *(const float4*)(convAcc + (row << 7) + c0);
  const float4 b = *(const float4*)(conv_b + c0);
  ushort4 pk;
  pk.x = f2b(v.x + b.x); pk.y = f2b(v.y + b.y);
  pk.z = f2b(v.z + b.z); pk.w = f2b(v.w + b.w);
  *(ushort4*)(qeb + row * 288 + c0) = pk;
}

// ---------- K3: h_psi attention logits, full 256 cols per block, direct store ----------
__global__ __launch_bounds__(512) void att_kernel(
    const u16* __restrict__ A, const u16* __restrict__ Bt,
    const float* __restrict__ bias, const float* __restrict__ vec,
    float* __restrict__ att) {
  __shared__ __align__(16) u16 lA[112 * 32];
  __shared__ __align__(16) u16 lB[256 * 32];
  __shared__ float attL[112];
  int tid = threadIdx.x, lane = tid & 63, w = tid >> 6;
  int r0 = blockIdx.x * 112;
  if (tid < 112) attL[tid] = 0.f;
  int kb = (((lane & 3) ^ ((lane >> 3) & 3)) << 3);
  const u16* gA0 = A + (size_t)(r0 + w * 16 + (lane >> 2)) * 288 + kb;
  const u16* gA1 = A + (size_t)(r0 + (w + 4) * 16 + (lane >> 2)) * 288 + kb;
  int wb = w - 4;

  f32x4 acc[7][2];
#pragma unroll
  for (int mt = 0; mt < 7; ++mt)
#pragma unroll
    for (int j = 0; j < 2; ++j) acc[mt][j] = (f32x4){0.f, 0.f, 0.f, 0.f};
  int l = lane & 15, q = lane >> 4;
  int co = ((q ^ ((l >> 1) & 3)) << 3);
  int colW = w * 32;                       // 8 waves cover 256 cols

  for (int cb = 0; cb < 9; ++cb) {
    __syncthreads();
    if (w < 4) {                           // waves 0-3 stage A (7 groups of 16 rows)
      g2l16(gA0 + cb * 32, &lA[w * 512]);
      if (w < 3) g2l16(gA1 + cb * 32, &lA[(w + 4) * 512]);
    } else {                               // waves 4-7 stage B (16 groups)
#pragma unroll
      for (int ii = 0; ii < 4; ++ii) {
        int g = wb * 4 + ii;
        g2l16(Bt + (size_t)(g * 16 + (lane >> 2)) * 288 + kb + cb * 32, &lB[g * 512]);
      }
    }
    __syncthreads();
    bf16x8 af[7];
#pragma unroll
    for (int mt = 0; mt < 7; ++mt)
      af[mt] = *(const bf16x8*)&lA[(mt * 16 + l) * 32 + co];
#pragma unroll
    for (int j = 0; j < 2; ++j) {
      bf16x8 bfr = *(const bf16x8*)&lB[(colW + j * 16 + l) * 32 + co];
#pragma unroll
      for (int mt = 0; mt < 7; ++mt)
        acc[mt][j] = __builtin_amdgcn_mfma_f32_16x16x32_bf16(af[mt], bfr, acc[mt][j], 0, 0, 0);
    }
  }
  float attp[7][4];
#pragma unroll
  for (int mt = 0; mt < 7; ++mt)
#pragma unroll
    for (int r = 0; r < 4; ++r) attp[mt][r] = 0.f;
#pragma unroll
  for (int j = 0; j < 2; ++j) {
    int col = colW + j * 16 + l;
    float b0 = bias[col], w1 = vec[col];
#pragma unroll
    for (int mt = 0; mt < 7; ++mt)
#pragma unroll
      for (int r = 0; r < 4; ++r) {
        float v = fmaxf(acc[mt][j][r] + b0, 0.f);
        attp[mt][r] += v * w1;
      }
  }
#pragma unroll
  for (int mt = 0; mt < 7; ++mt)
#pragma unroll
    for (int r = 0; r < 4; ++r) {
      float p = attp[mt][r];
      p += __shfl_xor(p, 1, 64);
      p += __shfl_xor(p, 2, 64);
      p += __shfl_xor(p, 4, 64);
      p += __shfl_xor(p, 8, 64);
      if (l == 0) atomicAdd(&attL[mt * 16 + q * 4 + r], p);
    }
  __syncthreads();
  if (tid < 112) att[r0 + tid] = attL[tid];
}

// ---------- generic GEMM skeleton (modes 1,2) ----------
template <int MODE, int KP, int KC>
__global__ __launch_bounds__(256) void gemm_kernel(
    const u16* __restrict__ A, const u16* __restrict__ Bt,
    const float* __restrict__ bias, const float* __restrict__ vec,
    float* __restrict__ outF, u16* __restrict__ outB) {
  __shared__ __align__(16) u16 lA[112 * 32];
  __shared__ __align__(16) u16 lB[128 * 32];
  int tid = threadIdx.x, lane = tid & 63, w = tid >> 6;
  int bx = blockIdx.x, by = blockIdx.y;
  int r0 = bx * 112;
  int cBase = by * 128;
  int kb = (((lane & 3) ^ ((lane >> 3) & 3)) << 3);
  int rA0 = r0 + w * 16 + (lane >> 2);
  int rA1 = r0 + (w + 4) * 16 + (lane >> 2);
  bool has1 = (w < 3);
  const u16* gA0 = A + (size_t)rA0 * KP + kb;
  const u16* gA1 = A + (size_t)rA1 * KP + kb;
  int cB0 = cBase + w * 16 + (lane >> 2);
  int cB1 = cBase + (w + 4) * 16 + (lane >> 2);
  const u16* gB0 = Bt + (size_t)cB0 * KP + kb;
  const u16* gB1 = Bt + (size_t)cB1 * KP + kb;

  f32x4 acc[7][2];
#pragma unroll
  for (int mt = 0; mt < 7; ++mt)
#pragma unroll
    for (int j = 0; j < 2; ++j) acc[mt][j] = (f32x4){0.f, 0.f, 0.f, 0.f};
  int colW = w * 32;
  int l = lane & 15, q = lane >> 4;
  int co = ((q ^ ((l >> 1) & 3)) << 3);

  for (int cb = 0; cb < KC; ++cb) {
    __syncthreads();
    g2l16(gA0 + cb * 32, &lA[w * 512]);
    if (has1) g2l16(gA1 + cb * 32, &lA[(w + 4) * 512]);
    g2l16(gB0 + cb * 32, &lB[w * 512]);
    g2l16(gB1 + cb * 32, &lB[(w + 4) * 512]);
    __syncthreads();
    bf16x8 af[7];
#pragma unroll
    for (int mt = 0; mt < 7; ++mt)
      af[mt] = *(const bf16x8*)&lA[(mt * 16 + l) * 32 + co];
#pragma unroll
    for (int j = 0; j < 2; ++j) {
      bf16x8 bfr = *(const bf16x8*)&lB[(colW + j * 16 + l) * 32 + co];
#pragma unroll
      for (int mt = 0; mt < 7; ++mt)
        acc[mt][j] = __builtin_amdgcn_mfma_f32_16x16x32_bf16(af[mt], bfr, acc[mt][j], 0, 0, 0);
    }
  }

  int q4 = lane >> 4, c = lane & 15;
  if (MODE == 1) {
    int n = bx >> 1;
#pragma unroll
    for (int mt = 0; mt < 7; ++mt)
#pragma unroll
      for (int j = 0; j < 2; ++j) {
        int col = cBase + colW + j * 16 + c;
        float b = bias[n * 256 + col];
#pragma unroll
        for (int r = 0; r < 4; ++r) {
          int row = r0 + mt * 16 + q4 * 4 + r;
          outB[(size_t)row * 256 + col] = f2b(fmaxf(acc[mt][j][r] + b, 0.f));
        }
      }
  } else {
    int n = bx >> 1;
    int ob = (bx & 1) * 112;
#pragma unroll
    for (int j = 0; j < 2; ++j) {
      int col = cBase + colW + j * 16 + c;
      float b = bias[col];
      float sum = 0.f;
#pragma unroll
      for (int mt = 0; mt < 7; ++mt)
#pragma unroll
        for (int r = 0; r < 4; ++r) {
          int o = ob + mt * 16 + q4 * 4 + r;
          if (o < 196) sum += fmaxf(acc[mt][j][r] + b, 0.f);
        }
      sum += __shfl_xor(sum, 16, 64);
      sum += __shfl_xor(sum, 32, 64);
      if (q4 == 0) atomicAdd(&outF[n * 256 + col], sum);
    }
  }
}

// ---------- K5: softmax over objects, soft-select, per-n bias2 ----------
__global__ __launch_bounds__(256) void sel_kernel(
    const float* __restrict__ att, const u16* __restrict__ qeb,
    const float* __restrict__ gt_w0, const float* __restrict__ gt_b0,
    float* __restrict__ bias2) {
  int n = blockIdx.x, t = threadIdx.x;
  int w = t >> 6, lane = t & 63;
  __shared__ u16 sq[196][130];
  __shared__ float sm[196];
  __shared__ float sel[130];
  __shared__ float red[8];
  const u16* base = qeb + (size_t)n * 224 * 288;
  for (int o = w; o < 196; o += 4) {
    const u16* rowp = base + (size_t)o * 288;
    for (int c = lane; c < 130; c += 64) sq[o][c] = rowp[c];
  }
  float a = (t < 196) ? att[n * 224 + t] : -1e30f;
  float m = a;
  for (int mask = 1; mask < 64; mask <<= 1) m = fmaxf(m, __shfl_xor(m, mask, 64));
  if (lane == 0) red[w] = m;
  __syncthreads();
  float M = fmaxf(fmaxf(red[0], red[1]), fmaxf(red[2], red[3]));
  float e = (t < 196) ? expf(a - M) : 0.f;
  float sAcc = e;
  for (int mask = 1; mask < 64; mask <<= 1) sAcc += __shfl_xor(sAcc, mask, 64);
  if (lane == 0) red[4 + w] = sAcc;
  __syncthreads();
  float S = red[4] + red[5] + red[6] + red[7];
  if (t < 196) sm[t] = e / S;
  __syncthreads();
  if (t < 130) {
    float acc = 0.f;
    for (int o = 0; o < 196; ++o) acc += sm[o] * b2f(sq[o][t]);
    sel[t] = acc;
  }
  __syncthreads();
  float acc2 = gt_b0[t];
  for (int d = 0; d < 130; ++d) acc2 += sel[d] * gt_w0[(258 + d) * 256 + t];
  bias2[n * 256 + t] = acc2;
}

// ---------- K8: f_phi ----------
__global__ __launch_bounds__(256) void fphi(
    const float* __restrict__ relations, const float* __restrict__ fp_w0,
    const float* __restrict__ fp_b0, const float* __restrict__ fp_w1,
    const float* __restrict__ fp_b1, float* __restrict__ out) {
  int n = blockIdx.x, t = threadIdx.x;
  __shared__ float rel[256];
  __shared__ float f[256];
  rel[t] = relations[n * 256 + t];
  __syncthreads();
  float acc = fp_b0[t];
  for (int k = 0; k < 256; ++k) acc += rel[k] * fp_w0[k * 256 + t];
  f[t] = fmaxf(acc, 0.f);
  __syncthreads();
  if (t < 32) {
    float o = fp_b1[0];
    for (int k = 0; k < 256; ++k) o += f[k] * fp_w1[k * 32 + t];
    out[n * 32 + t] = o;
  }
}

extern "C" void kernel_launch(void* const* d_in, const int* in_sizes, int n_in,
                              void* d_out, int out_size, void* d_ws, size_t ws_size,
                              hipStream_t stream) {
  const float* image = (const float*)d_in[0];
  const float* code = (const float*)d_in[1];
  const float* conv_w = (const float*)d_in[2];
  const float* conv_b = (const float*)d_in[3];
  const float* hp_w0 = (const float*)d_in[4];
  const float* hp_b0 = (const float*)d_in[5];
  const float* hp_w1 = (const float*)d_in[6];
  /* hp_b1: softmax shift-invariant, dropped */
  const float* gt_w0 = (const float*)d_in[8];
  const float* gt_b0 = (const float*)d_in[9];
  const float* gt_w1 = (const float*)d_in[10];
  const float* gt_b1 = (const float*)d_in[11];
  const float* fp_w0 = (const float*)d_in[12];
  const float* fp_b0 = (const float*)d_in[13];
  const float* fp_w1 = (const float*)d_in[14];
  const float* fp_b1 = (const float*)d_in[15];
  float* out = (float*)d_out;

  char* p = (char*)d_ws;
  u16* imgT = (u16*)p;   p += (size_t)128 * 256 * 1024 * 2;   // 67.1 MB
  u16* W2 = (u16*)p;     p += (size_t)9 * 128 * 1024 * 2;     // 2.36 MB
  u16* qeb = (u16*)p;    p += (size_t)ROWS * 288 * 2;         // 16.5 MB
  u16* hp_w0t = (u16*)p; p += (size_t)256 * 288 * 2;
  u16* gt_w0t = (u16*)p; p += (size_t)256 * 288 * 2;
  u16* gt_w1t = (u16*)p; p += (size_t)256 * 256 * 2;
  float* att = (float*)p;   p += (size_t)ROWS * 4;
  float* bias2 = (float*)p; p += (size_t)128 * 256 * 4;
  float* convAcc = (float*)p; p += (size_t)ROWS * 128 * 4;    // 14.7 MB; reused as g1
  float* relations = (float*)p; p += (size_t)128 * 256 * 4;
  u16* g1 = (u16*)convAcc;   // alias: convAcc dead after conv_fix

  prep_misc<<<5088, 256, 0, stream>>>(conv_w, hp_w0, gt_w0, gt_w1, code,
                                      W2, hp_w0t, gt_w0t, gt_w1t, qeb, convAcc, relations);
  prep_img<<<2048, 256, 0, stream>>>(image, imgT);
  conv_gemm<<<1024, 256, 0, stream>>>(imgT, W2, convAcc);
  conv_fix<<<3136, 256, 0, stream>>>(convAcc, conv_b, qeb);
  att_kernel<<<256, 512, 0, stream>>>(qeb, hp_w0t, hp_b0, hp_w1, att);
  sel_kernel<<<128, 256, 0, stream>>>(att, qeb, gt_w0, gt_b0, bias2);
  gemm_kernel<1, 288, 9><<<dim3(256, 2), 256, 0, stream>>>(qeb, gt_w0t, bias2, nullptr, nullptr, g1);
  gemm_kernel<2, 256, 8><<<dim3(256, 2), 256, 0, stream>>>(g1, gt_w1t, gt_b1, nullptr, relations, nullptr);
  fphi<<<128, 256, 0, stream>>>(relations, fp_w0, fp_b0, fp_w1, fp_b1, out);
}